// Round 8
// baseline (1997.459 us; speedup 1.0000x reference)
//
#include <hip/hip_runtime.h>

// ---------------------------------------------------------------------------
// HeadsSelection: emb-gather -> 2x bidirectional LSTM -> additive attention
// S=256, B=16, V=20000, E=512, H=256, L=2, HM=128
// Round 8: single-barrier recurrence step.
//   - Gate-interleaved A-rows (m = unit_off*4 + gate): MFMA C layout puts all
//     4 gates of one (unit,batch) into ONE lane's accumulator regs -> the
//     LSTM nonlinearity + publish run in-register. No Lg tile, no 2nd barrier.
//   - hL double-buffered by step parity; one __syncthreads per step.
//   - Staging: 4 x global_load_dwordx4 sc1 per lane (8 u64 entries), stamp-
//     retry per 16B packet. Gin loads issued after the poll (not drained by
//     the poll's vmcnt(0)); consumed ~24 MFMAs later.
//   - G in TRANS [n][4096] layout: GEMM float4 stores, lstm 64B-chunk reads.
//   - R7's split-bf16 MFMA GEMM (k_gemm_pk) kept, epilogue now TRANS.
// ---------------------------------------------------------------------------

#define S_    256
#define B_    16
#define E_    512
#define H_    256
#define HM_   128
#define M_    4096   // S*B

typedef __attribute__((ext_vector_type(8))) short short8;
typedef __attribute__((ext_vector_type(4))) float f32x4;
typedef __attribute__((ext_vector_type(4))) unsigned int u32x4v;
union u32x4s8 { unsigned int u[4]; uint4 u4; short8 v; };

__device__ __forceinline__ float sigm(float x) { return 1.f / (1.f + __expf(-x)); }
__device__ __forceinline__ float tanh_fast(float x) {
  x = fminf(fmaxf(x, -15.f), 15.f);
  float e = __expf(2.f * x);
  return (e - 1.f) / (e + 1.f);
}
__device__ __forceinline__ unsigned short f2bf(float f) {
  unsigned u = __float_as_uint(f);
  u += 0x7FFFu + ((u >> 16) & 1u);
  return (unsigned short)(u >> 16);
}
__device__ __forceinline__ float bf2f(unsigned short s) {
  return __uint_as_float(((unsigned)s) << 16);
}
__device__ __forceinline__ unsigned int packsplit(float f) {
  unsigned short m = f2bf(f);
  unsigned short r = f2bf(f - bf2f(m));
  return (unsigned)m | ((unsigned)r << 16);
}

// 4 x 16B agent-coherent loads (2 u64 Hbuf entries each), one drain.
__device__ __forceinline__ void stage4_sc1(u32x4v v[4], const u32x4v* p) {
  asm volatile(
      "global_load_dwordx4 %0, %4, off sc1\n\t"
      "global_load_dwordx4 %1, %4, off offset:1024 sc1\n\t"
      "global_load_dwordx4 %2, %4, off offset:2048 sc1\n\t"
      "global_load_dwordx4 %3, %4, off offset:3072 sc1\n\t"
      "s_waitcnt vmcnt(0)"
      : "=&v"(v[0]), "=&v"(v[1]), "=&v"(v[2]), "=&v"(v[3])
      : "v"(p)
      : "memory");
}
__device__ __forceinline__ u32x4v stage1_sc1(const u32x4v* p) {
  u32x4v r;
  asm volatile("global_load_dwordx4 %0, %1, off sc1\n\ts_waitcnt vmcnt(0)"
               : "=v"(r) : "v"(p) : "memory");
  return r;
}

// ---------------------------------------------------------------- gather ----
__global__ void k_gather_pk(const int* __restrict__ concepts, const float* __restrict__ emb,
                            unsigned int* __restrict__ Xpk) {
  int m = blockIdx.x;
  int tok = concepts[m];
  const float4* src = reinterpret_cast<const float4*>(emb + (size_t)tok * E_);
  uint4* dst = reinterpret_cast<uint4*>(Xpk + (size_t)m * E_);
  for (int i = threadIdx.x; i < E_ / 4; i += blockDim.x) {
    float4 v = src[i];
    uint4 o;
    o.x = packsplit(v.x); o.y = packsplit(v.y); o.z = packsplit(v.z); o.w = packsplit(v.w);
    dst[i] = o;
  }
}

// ------------------------------------------------------------------ pack ----
__global__ void k_pack(const float* __restrict__ in, unsigned int* __restrict__ out, int n4) {
  int i = blockIdx.x * blockDim.x + threadIdx.x;
  if (i < n4) {
    float4 v = reinterpret_cast<const float4*>(in)[i];
    uint4 o;
    o.x = packsplit(v.x); o.y = packsplit(v.y); o.z = packsplit(v.z); o.w = packsplit(v.w);
    reinterpret_cast<uint4*>(out)[i] = o;
  }
}

// ------------------------------------------------------------- MFMA GEMM ----
// C^T store: C[n][m], m stride 4096. A/W packed split-bf16 u32; 3-product.
__global__ __launch_bounds__(256) void k_gemm_pk(const unsigned int* __restrict__ Apk,
                                                 const unsigned int* __restrict__ Wpk,
                                                 const float* __restrict__ bias,
                                                 float* __restrict__ C, int K) {
  __shared__ unsigned int As[128][36];
  __shared__ unsigned int Ws2[128][36];
  const int bm = blockIdx.x * 128, bn = blockIdx.y * 128;
  const int tid = threadIdx.x;
  const int wave = tid >> 6, lane = tid & 63;
  const int wm = (wave >> 1) << 6, wn = (wave & 1) << 6;
  const int l16 = lane & 15, quad = lane >> 4;
  const int r = tid >> 1, cb = (tid & 1) << 4;

  f32x4 acc[4][4];
#pragma unroll
  for (int i = 0; i < 4; ++i)
#pragma unroll
    for (int j = 0; j < 4; ++j) acc[i][j] = (f32x4){0.f, 0.f, 0.f, 0.f};

  for (int k0 = 0; k0 < K; k0 += 32) {
    const unsigned int* pa = Apk + (size_t)(bm + r) * K + k0 + cb;
    const unsigned int* pw = Wpk + (size_t)(bn + r) * K + k0 + cb;
    uint4 a0 = *(const uint4*)pa, a1 = *(const uint4*)(pa + 4),
          a2 = *(const uint4*)(pa + 8), a3 = *(const uint4*)(pa + 12);
    uint4 w0 = *(const uint4*)pw, w1 = *(const uint4*)(pw + 4),
          w2 = *(const uint4*)(pw + 8), w3 = *(const uint4*)(pw + 12);
    __syncthreads();
    *(uint4*)&As[r][cb] = a0;  *(uint4*)&As[r][cb + 4] = a1;
    *(uint4*)&As[r][cb + 8] = a2; *(uint4*)&As[r][cb + 12] = a3;
    *(uint4*)&Ws2[r][cb] = w0; *(uint4*)&Ws2[r][cb + 4] = w1;
    *(uint4*)&Ws2[r][cb + 8] = w2; *(uint4*)&Ws2[r][cb + 12] = w3;
    __syncthreads();

    short8 Amv[4], Arv[4], Bmv[4], Brv[4];
#pragma unroll
    for (int t = 0; t < 4; ++t) {
      const unsigned int* p = &As[wm + (t << 4) + l16][quad << 3];
      uint4 p0 = *(const uint4*)p, p1 = *(const uint4*)(p + 4);
      u32x4s8 m, rr;
      m.u[0] = __builtin_amdgcn_perm(p0.y, p0.x, 0x05040100u);
      rr.u[0] = __builtin_amdgcn_perm(p0.y, p0.x, 0x07060302u);
      m.u[1] = __builtin_amdgcn_perm(p0.w, p0.z, 0x05040100u);
      rr.u[1] = __builtin_amdgcn_perm(p0.w, p0.z, 0x07060302u);
      m.u[2] = __builtin_amdgcn_perm(p1.y, p1.x, 0x05040100u);
      rr.u[2] = __builtin_amdgcn_perm(p1.y, p1.x, 0x07060302u);
      m.u[3] = __builtin_amdgcn_perm(p1.w, p1.z, 0x05040100u);
      rr.u[3] = __builtin_amdgcn_perm(p1.w, p1.z, 0x07060302u);
      Amv[t] = m.v; Arv[t] = rr.v;
      const unsigned int* pb = &Ws2[wn + (t << 4) + l16][quad << 3];
      uint4 q0 = *(const uint4*)pb, q1 = *(const uint4*)(pb + 4);
      m.u[0] = __builtin_amdgcn_perm(q0.y, q0.x, 0x05040100u);
      rr.u[0] = __builtin_amdgcn_perm(q0.y, q0.x, 0x07060302u);
      m.u[1] = __builtin_amdgcn_perm(q0.w, q0.z, 0x05040100u);
      rr.u[1] = __builtin_amdgcn_perm(q0.w, q0.z, 0x07060302u);
      m.u[2] = __builtin_amdgcn_perm(q1.y, q1.x, 0x05040100u);
      rr.u[2] = __builtin_amdgcn_perm(q1.y, q1.x, 0x07060302u);
      m.u[3] = __builtin_amdgcn_perm(q1.w, q1.z, 0x05040100u);
      rr.u[3] = __builtin_amdgcn_perm(q1.w, q1.z, 0x07060302u);
      Bmv[t] = m.v; Brv[t] = rr.v;
    }
#pragma unroll
    for (int ti = 0; ti < 4; ++ti)
#pragma unroll
      for (int tj = 0; tj < 4; ++tj) {
        acc[ti][tj] = __builtin_amdgcn_mfma_f32_16x16x32_bf16(Amv[ti], Bmv[tj], acc[ti][tj], 0, 0, 0);
        acc[ti][tj] = __builtin_amdgcn_mfma_f32_16x16x32_bf16(Amv[ti], Brv[tj], acc[ti][tj], 0, 0, 0);
        acc[ti][tj] = __builtin_amdgcn_mfma_f32_16x16x32_bf16(Arv[ti], Bmv[tj], acc[ti][tj], 0, 0, 0);
      }
  }

#pragma unroll
  for (int tj = 0; tj < 4; ++tj) {
    float bv = bias ? bias[bn + wn + (tj << 4) + l16] : 0.f;
#pragma unroll
    for (int ti = 0; ti < 4; ++ti) {
      float4 vv = make_float4(acc[ti][tj][0] + bv, acc[ti][tj][1] + bv,
                              acc[ti][tj][2] + bv, acc[ti][tj][3] + bv);
      *(float4*)(C + (size_t)(bn + wn + (tj << 4) + l16) * 4096 +
                 bm + wm + (ti << 4) + (quad << 2)) = vv;
    }
  }
}

// ------------------------------------------------------------- fp32 GEMM ----
// (projections: N=128) row-major C[m][N]
__global__ __launch_bounds__(256) void k_gemm(const float* __restrict__ A,
                                              const float* __restrict__ W,
                                              float* __restrict__ C,
                                              int M, int N, int K) {
  __shared__ __align__(16) float As[16][132];
  __shared__ __align__(16) float Ws[16][132];
  const int bm = blockIdx.x * 128, bn = blockIdx.y * 128;
  const int tid = threadIdx.x;
  const int tm = (tid >> 4) * 8, tn = (tid & 15) * 8;
  float acc[8][8];
#pragma unroll
  for (int i = 0; i < 8; i++)
#pragma unroll
    for (int j = 0; j < 8; j++) acc[i][j] = 0.f;

  const int lr = tid >> 1, lk = (tid & 1) * 8;
  for (int k0 = 0; k0 < K; k0 += 16) {
    float4 a0 = *(const float4*)(A + (size_t)(bm + lr) * K + k0 + lk);
    float4 a1 = *(const float4*)(A + (size_t)(bm + lr) * K + k0 + lk + 4);
    float4 w0 = *(const float4*)(W + (size_t)(bn + lr) * K + k0 + lk);
    float4 w1 = *(const float4*)(W + (size_t)(bn + lr) * K + k0 + lk + 4);
    As[lk + 0][lr] = a0.x; As[lk + 1][lr] = a0.y; As[lk + 2][lr] = a0.z; As[lk + 3][lr] = a0.w;
    As[lk + 4][lr] = a1.x; As[lk + 5][lr] = a1.y; As[lk + 6][lr] = a1.z; As[lk + 7][lr] = a1.w;
    Ws[lk + 0][lr] = w0.x; Ws[lk + 1][lr] = w0.y; Ws[lk + 2][lr] = w0.z; Ws[lk + 3][lr] = w0.w;
    Ws[lk + 4][lr] = w1.x; Ws[lk + 5][lr] = w1.y; Ws[lk + 6][lr] = w1.z; Ws[lk + 7][lr] = w1.w;
    __syncthreads();
#pragma unroll
    for (int k = 0; k < 16; k++) {
      float4 av0 = *(const float4*)&As[k][tm];
      float4 av1 = *(const float4*)&As[k][tm + 4];
      float4 wv0 = *(const float4*)&Ws[k][tn];
      float4 wv1 = *(const float4*)&Ws[k][tn + 4];
      float a[8] = {av0.x, av0.y, av0.z, av0.w, av1.x, av1.y, av1.z, av1.w};
      float w[8] = {wv0.x, wv0.y, wv0.z, wv0.w, wv1.x, wv1.y, wv1.z, wv1.w};
#pragma unroll
      for (int i = 0; i < 8; i++)
#pragma unroll
        for (int j = 0; j < 8; j++) acc[i][j] += a[i] * w[j];
    }
    __syncthreads();
  }
#pragma unroll
  for (int i = 0; i < 8; i++) {
    float4 v0 = make_float4(acc[i][0], acc[i][1], acc[i][2], acc[i][3]);
    float4 v1 = make_float4(acc[i][4], acc[i][5], acc[i][6], acc[i][7]);
    *(float4*)(C + (size_t)(bm + tm + i) * N + bn + tn) = v0;
    *(float4*)(C + (size_t)(bm + tm + i) * N + bn + tn + 4) = v1;
  }
}

// ------------------------------------------------------------- LSTM layer ----
// Grid: 32 WGs = dir(2) x g(16), 512 thr (8 waves). Waves 0-3 (t=w8): MFMA
// tile with A rows m = unit_off*4 + gate (units g*16+t*4+[0,4), 4 gates) ->
// lane (quad,bcol) ends with all 4 gates of (unit=g*16+t*4+quad, batch=bcol)
// in its 4 acc regs: in-register nonlinearity + publish. All 8 waves stage
// (4 x 16B sc1 loads = 8 u64 entries/lane) into parity-buffered hL.
// Gin: TRANS [2048][4096]. Hbuf entry u64 {stamp, packed split-bf16 h}.
__global__ __launch_bounds__(512) void k_lstm(const float* __restrict__ Gin,
                                              const float* __restrict__ whh,
                                              float* __restrict__ Houtf,
                                              unsigned int* __restrict__ Houtp,
                                              unsigned long long* __restrict__ Hbuf) {
  const int d = blockIdx.x >> 4;
  const int g = blockIdx.x & 15;
  const int tid = threadIdx.x;
  const int w8 = tid >> 6;
  const int lane = tid & 63;
  const int bcol = lane & 15;
  const int quad = lane >> 4;
  const int ws = (w8 + g) & 7;
  __shared__ __align__(16) unsigned int hL[2 * 4160];   // [parity][b*260+k]

  // ---- one-time A fragments: row m=bcol -> gate=bcol&3, unit_off=bcol>>2 ----
  unsigned int Am[8][4], Ar[8][4];
  if (w8 < 4) {
    const int unit = (g << 4) + (w8 << 2) + (bcol >> 2);
    const float* wrow = whh + (size_t)((d << 10) + ((bcol & 3) << 8) + unit) * 256;
#pragma unroll
    for (int s = 0; s < 8; ++s) {
      float w[8];
      *(float4*)&w[0] = *(const float4*)(wrow + s * 32 + quad * 8);
      *(float4*)&w[4] = *(const float4*)(wrow + s * 32 + quad * 8 + 4);
#pragma unroll
      for (int j = 0; j < 4; ++j) {
        unsigned short m0 = f2bf(w[2 * j]), m1 = f2bf(w[2 * j + 1]);
        unsigned short r0 = f2bf(w[2 * j] - bf2f(m0));
        unsigned short r1 = f2bf(w[2 * j + 1] - bf2f(m1));
        Am[s][j] = (unsigned)m0 | ((unsigned)m1 << 16);
        Ar[s][j] = (unsigned)r0 | ((unsigned)r1 << 16);
      }
    }
  }

  const int unit_e = (g << 4) + (w8 << 2) + quad;       // this lane's unit (waves 0-3)
  float c_reg = 0.f;
  for (int it = 0; it < 256; ++it) {
    const int step = d ? (255 - it) : it;

    // ---- stage h_prev: 4 x 16B sc1 loads, stamp-retry per packet ----
    if (it > 0) {
      const u32x4v* src =
          (const u32x4v*)(Hbuf + ((size_t)((d << 1) + ((it - 1) & 1)) << 12));
      const u32x4v* p0 = src + (ws << 8) + lane;
      const unsigned int want = (unsigned int)it;
      u32x4v v[4];
      stage4_sc1(v, p0);
      for (;;) {
        unsigned int badm = 0;
#pragma unroll
        for (int c = 0; c < 4; ++c)
          badm |= ((v[c].y != want) | (v[c].w != want)) ? (1u << c) : 0u;
        if (__ballot(badm != 0) == 0ull) break;
#pragma unroll
        for (int c = 0; c < 4; ++c)
          if (badm & (1u << c)) v[c] = stage1_sc1(p0 + (c << 6));
      }
      unsigned int* dL = &hL[(it & 1) * 4160];
#pragma unroll
      for (int c = 0; c < 4; ++c) {
        int b = (ws << 1) + (c >> 1);
        int k = ((c & 1) << 7) + (lane << 1);
        *(unsigned long long*)&dL[b * 260 + k] =
            (unsigned long long)v[c].x | ((unsigned long long)v[c].z << 32);
      }
    }

    // ---- Gin loads (after poll so its vmcnt(0) doesn't drain them) ----
    float gin[4];
    if (w8 < 4) {
#pragma unroll
      for (int gate = 0; gate < 4; ++gate)
        gin[gate] = Gin[((size_t)((d << 10) + (gate << 8) + unit_e) << 12) + (step << 4) + bcol];
    }
    __syncthreads();

    // ---- MFMA + in-register epilogue (waves 0-3) ----
    if (w8 < 4) {
      f32x4 acc0 = {0.f, 0.f, 0.f, 0.f}, acc1 = acc0, acc2 = acc0;
      if (it > 0) {
        const unsigned int* hb = &hL[(it & 1) * 4160];
#pragma unroll
        for (int s = 0; s < 8; ++s) {
          const unsigned int* p = &hb[bcol * 260 + (s << 5) + (quad << 3)];
          uint4 p0v = *(const uint4*)p;
          uint4 p1v = *(const uint4*)(p + 4);
          u32x4s8 Bm, Br, Amu, Aru;
          Bm.u[0] = __builtin_amdgcn_perm(p0v.y, p0v.x, 0x05040100u);
          Br.u[0] = __builtin_amdgcn_perm(p0v.y, p0v.x, 0x07060302u);
          Bm.u[1] = __builtin_amdgcn_perm(p0v.w, p0v.z, 0x05040100u);
          Br.u[1] = __builtin_amdgcn_perm(p0v.w, p0v.z, 0x07060302u);
          Bm.u[2] = __builtin_amdgcn_perm(p1v.y, p1v.x, 0x05040100u);
          Br.u[2] = __builtin_amdgcn_perm(p1v.y, p1v.x, 0x07060302u);
          Bm.u[3] = __builtin_amdgcn_perm(p1v.w, p1v.z, 0x05040100u);
          Br.u[3] = __builtin_amdgcn_perm(p1v.w, p1v.z, 0x07060302u);
#pragma unroll
          for (int j = 0; j < 4; ++j) { Amu.u[j] = Am[s][j]; Aru.u[j] = Ar[s][j]; }
          acc0 = __builtin_amdgcn_mfma_f32_16x16x32_bf16(Amu.v, Bm.v, acc0, 0, 0, 0);
          acc1 = __builtin_amdgcn_mfma_f32_16x16x32_bf16(Amu.v, Br.v, acc1, 0, 0, 0);
          acc2 = __builtin_amdgcn_mfma_f32_16x16x32_bf16(Aru.v, Bm.v, acc2, 0, 0, 0);
        }
      }
      f32x4 t = acc0 + acc1 + acc2;
      // lane holds gates i,f,g,o of (unit_e, batch=bcol) in t[0..3]
      float ct = sigm(t[1] + gin[1]) * c_reg + sigm(t[0] + gin[0]) * tanh_fast(t[2] + gin[2]);
      c_reg = ct;
      float h = sigm(t[3] + gin[3]) * tanh_fast(ct);
      unsigned short hm = f2bf(h);
      unsigned short hr = f2bf(h - bf2f(hm));
      unsigned int hpk = ((unsigned)hr << 16) | (unsigned)hm;
      unsigned long long hp = ((unsigned long long)(unsigned int)(it + 1) << 32) |
                              (unsigned long long)hpk;
      __hip_atomic_store(Hbuf + ((size_t)((d << 1) + (it & 1)) << 12) + (bcol << 8) + unit_e,
                         hp, __ATOMIC_RELAXED, __HIP_MEMORY_SCOPE_AGENT);
      size_t oidx = (size_t)((step << 4) + bcol) * 512 + (d << 8) + unit_e;
      Houtf[oidx] = h;
      Houtp[oidx] = hpk;
    }
    // no second barrier: hL is parity-buffered; barrier ordering guarantees
    // iter-it reads complete before any wave can write hL[it&1] again (it+2).
  }
}

// ------------------------------------------------------------- attention ----
__global__ __launch_bounds__(256) void k_attn(const float* __restrict__ P,
                                              const float* __restrict__ Cc,
                                              const float* __restrict__ va,
                                              float* __restrict__ out) {
  const int b = blockIdx.x & 15, i = blockIdx.x >> 4;
  __shared__ float pv[128], vv[128];
  const int t = threadIdx.x;
  if (t < 128) {
    pv[t] = P[(size_t)((i << 4) + b) * 128 + t];
    vv[t] = va[t];
  }
  __syncthreads();
  const float4* c4 = reinterpret_cast<const float4*>(Cc + (size_t)((t << 4) + b) * 128);
  float acc = 0.f;
#pragma unroll 8
  for (int hh = 0; hh < 32; ++hh) {
    float4 cv = c4[hh];
    int h = hh << 2;
    acc += vv[h]     * tanh_fast(pv[h]     + cv.x);
    acc += vv[h + 1] * tanh_fast(pv[h + 1] + cv.y);
    acc += vv[h + 2] * tanh_fast(pv[h + 2] + cv.z);
    acc += vv[h + 3] * tanh_fast(pv[h + 3] + cv.w);
  }
  size_t o = ((size_t)b << 16) + ((size_t)i << 8) + (size_t)t;
  out[o] = acc;
  out[(1u << 20) + o] = (acc >= 0.f) ? 1.f : 0.f;
}

// --------------------------------------------------------------- launch ----
extern "C" void kernel_launch(void* const* d_in, const int* in_sizes, int n_in,
                              void* d_out, int out_size, void* d_ws, size_t ws_size,
                              hipStream_t stream) {
  const int*   concepts = (const int*)d_in[0];
  const float* emb  = (const float*)d_in[2];
  const float* w_ih = (const float*)d_in[3];   // [2][2][1024][512]
  const float* w_hh = (const float*)d_in[4];   // [2][2][1024][256]
  const float* bias = (const float*)d_in[5];   // [2][2][1024]
  const float* Ua   = (const float*)d_in[6];   // [128][512]
  const float* Wa   = (const float*)d_in[7];   // [128][512]
  const float* va   = (const float*)d_in[8];   // [1][128]
  float* out = (float*)d_out;
  float* ws  = (float*)d_ws;

  constexpr size_t OFF_G   = 0;                               // [2048][4096] f32 (TRANS)
  constexpr size_t OFF_PK  = OFF_G  + (size_t)M_ * 2048;      // Xpk/H0pk/H1pk u32 [4096][512]
  constexpr size_t OFF_WPK = OFF_PK + (size_t)M_ * 512;       // Wpk u32 [2][2048][512]
  constexpr size_t OFF_HF  = OFF_WPK + 2 * 2048 * 512;        // H f32 [4096][512]
  constexpr size_t OFF_P   = OFF_HF + (size_t)M_ * 512;       // Pm [4096][128]
  constexpr size_t OFF_C   = OFF_P  + (size_t)M_ * HM_;       // Cm [4096][128]
  constexpr size_t OFF_HB  = OFF_C  + (size_t)M_ * HM_;       // Hbuf u64 x2 layers

  float* G  = ws + OFF_G;
  unsigned int* PK  = (unsigned int*)(ws + OFF_PK);
  unsigned int* WPK = (unsigned int*)(ws + OFF_WPK);
  float* HF = ws + OFF_HF;
  float* Pm = ws + OFF_P;
  float* Cm = ws + OFF_C;
  unsigned long long* Hb0 = (unsigned long long*)(ws + OFF_HB);
  unsigned long long* Hb1 = Hb0 + 2 * 2 * 4096;

  k_pack<<<(2 * 2048 * 512 / 4 + 255) / 256, 256, 0, stream>>>(w_ih, WPK, 2 * 2048 * 512 / 4);
  k_gather_pk<<<M_, 128, 0, stream>>>(concepts, emb, PK);

  // layer 0
  k_gemm_pk<<<dim3(32, 16), 256, 0, stream>>>(PK, WPK, bias, G, 512);
  k_lstm<<<32, 512, 0, stream>>>(G, w_hh, HF, PK, Hb0);   // PK becomes H0pk

  // layer 1
  k_gemm_pk<<<dim3(32, 16), 256, 0, stream>>>(PK, WPK + (size_t)2048 * 512, bias + 2048, G, 512);
  k_lstm<<<32, 512, 0, stream>>>(G, w_hh + (size_t)2048 * 256, HF, PK, Hb1);  // HF = H1

  // attention projections
  k_gemm<<<dim3(32, 1), 256, 0, stream>>>(HF, Ua, Pm, M_, HM_, 512);
  k_gemm<<<dim3(32, 1), 256, 0, stream>>>(HF, Wa, Cm, M_, HM_, 512);

  k_attn<<<M_, 256, 0, stream>>>(Pm, Cm, va, out);
}